// Round 10
// baseline (276.107 us; speedup 1.0000x reference)
//
#include <hip/hip_runtime.h>

typedef float          f32x4    __attribute__((ext_vector_type(4)));
typedef float          f32x16   __attribute__((ext_vector_type(16)));
typedef float          float8v  __attribute__((ext_vector_type(8)));
typedef unsigned short ushort4v __attribute__((ext_vector_type(4)));
typedef unsigned short ushort8v __attribute__((ext_vector_type(8)));
typedef __bf16         bf16x8   __attribute__((ext_vector_type(8)));

__device__ __forceinline__ unsigned short f2b(float x) {
  union { __bf16 b; unsigned short u; } v;
  v.b = (__bf16)x;                       // hw v_cvt (RNE) on gfx950
  return v.u;
}
__device__ __forceinline__ float b2f(unsigned short h) {
  union { unsigned u; float f; } v; v.u = ((unsigned)h) << 16;
  return v.f;
}
// drain LDS ops of THIS wave without touching vmcnt (keeps prefetch in flight)
__device__ __forceinline__ void lds_fence() {
  __builtin_amdgcn_wave_barrier();
  asm volatile("s_waitcnt lgkmcnt(0)" ::: "memory");
}

// async global->LDS, 16B per lane; LDS dest = wave-uniform base + lane*16
__device__ __forceinline__ void g2lds16(const unsigned short* g,
                                        unsigned short* l) {
  __builtin_amdgcn_global_load_lds(
      (const __attribute__((address_space(1))) unsigned int*)g,
      (__attribute__((address_space(3))) unsigned int*)l, 16, 0, 0);
}

// ---------------- f32 -> bf16 convert, 8 elems/thread ----------------
__global__ void cvt_kernel(const float* __restrict__ src,
                           unsigned short* __restrict__ dst, int n8) {
  int i = blockIdx.x * 256 + threadIdx.x;
  if (i >= n8) return;
  float8v v = reinterpret_cast<const float8v*>(src)[i];
  ushort8v h;
#pragma unroll
  for (int j = 0; j < 8; ++j) h[j] = f2b(v[j]);
  reinterpret_cast<ushort8v*>(dst)[i] = h;
}

// -------- weight transpose+convert: W(f32)[K][N] -> WT(bf16)[N][K] --------
__global__ __launch_bounds__(256) void wtrans_kernel(
    const float* __restrict__ W, unsigned short* __restrict__ WT,
    int K, int N) {
  __shared__ unsigned short T[64 * 72];
  const int tid = threadIdx.x;
  const int n0 = blockIdx.x * 64, k0 = blockIdx.y * 64;
#pragma unroll
  for (int it = 0; it < 2; ++it) {
    int c = tid + it * 256;               // [0,512)
    int r = c >> 3, cc = c & 7;
    float8v v = *reinterpret_cast<const float8v*>(
        &W[(size_t)(k0 + r) * N + n0 + cc * 8]);
    ushort8v h;
#pragma unroll
    for (int j = 0; j < 8; ++j) h[j] = f2b(v[j]);
    *reinterpret_cast<ushort8v*>(&T[r * 72 + cc * 8]) = h;
  }
  __syncthreads();
#pragma unroll
  for (int it = 0; it < 2; ++it) {
    int c = tid + it * 256;
    int n = c >> 3, kc = c & 7;
    ushort8v y;
#pragma unroll
    for (int j = 0; j < 8; ++j) y[j] = T[(kc * 8 + j) * 72 + n];
    *reinterpret_cast<ushort8v*>(&WT[(size_t)(n0 + n) * K + k0 + kc * 8]) = y;
  }
}

// ---------------- generic gemm_bt (round-6 single-buffer) ----------------
template <int TM, typename CT, bool ACC>
__global__ __launch_bounds__(256) void gemm_bt(
    const unsigned short* __restrict__ A, const unsigned short* __restrict__ Bt,
    CT* __restrict__ C, int M, int N, int K) {
  __shared__ unsigned short As[TM * 64];
  __shared__ unsigned short Bs[128 * 64];
  const int tid = threadIdx.x;
  const int m0 = blockIdx.y * TM, n0 = blockIdx.x * 128;
  const int wave = tid >> 6, lane = tid & 63;
  const int wm = (wave >> 1) * (TM / 2), wn = (wave & 1) * 64;
  const int l16 = lane & 15, quad = lane >> 4;
  constexpr int MI = TM / 32;

  f32x4 acc[MI][4];
#pragma unroll
  for (int i = 0; i < MI; ++i)
#pragma unroll
    for (int j = 0; j < 4; ++j)
#pragma unroll
      for (int r = 0; r < 4; ++r) acc[i][j][r] = 0.f;

  for (int k0 = 0; k0 < K; k0 += 64) {
    __syncthreads();
#pragma unroll
    for (int it = 0; it < TM * 8 / 256; ++it) {
      int c = it * 256 + tid;
      int m = c >> 3, kc = (c & 7) ^ (m & 7);
      g2lds16(&A[(size_t)(m0 + m) * K + k0 + kc * 8], &As[c * 8]);
    }
#pragma unroll
    for (int it = 0; it < 4; ++it) {
      int c = it * 256 + tid;
      int n = c >> 3, kc = (c & 7) ^ (n & 7);
      g2lds16(&Bt[(size_t)(n0 + n) * K + k0 + kc * 8], &Bs[c * 8]);
    }
    __syncthreads();

#pragma unroll
    for (int ks = 0; ks < 2; ++ks) {
      bf16x8 af[MI], bfr[4];
#pragma unroll
      for (int mi = 0; mi < MI; ++mi) {
        int m = wm + mi * 16 + l16;
        af[mi] = *reinterpret_cast<const bf16x8*>(
            &As[(m * 8 + ((ks * 4 + quad) ^ (m & 7))) * 8]);
      }
#pragma unroll
      for (int ni = 0; ni < 4; ++ni) {
        int n = wn + ni * 16 + l16;
        bfr[ni] = *reinterpret_cast<const bf16x8*>(
            &Bs[(n * 8 + ((ks * 4 + quad) ^ (n & 7))) * 8]);
      }
#pragma unroll
      for (int mi = 0; mi < MI; ++mi)
#pragma unroll
        for (int ni = 0; ni < 4; ++ni)
          acc[mi][ni] = __builtin_amdgcn_mfma_f32_16x16x32_bf16(
              af[mi], bfr[ni], acc[mi][ni], 0, 0, 0);
    }
  }

#pragma unroll
  for (int mi = 0; mi < MI; ++mi)
#pragma unroll
    for (int ni = 0; ni < 4; ++ni) {
      int row = m0 + wm + mi * 16 + quad * 4;
      int col = n0 + wn + ni * 16 + l16;
#pragma unroll
      for (int r = 0; r < 4; ++r) {
        size_t idx = (size_t)(row + r) * N + col;
        float val = acc[mi][ni][r];
        if constexpr (sizeof(CT) == 2) {
          if constexpr (ACC) val += b2f(C[idx]);
          C[idx] = f2b(val);
        } else {
          if constexpr (ACC) val += C[idx];
          C[idx] = val;
        }
      }
    }
}

// ------- fused GEMM #1: [q_r | k_r | c_kv] = X @ [wqr|wkr|wkvc]^T -------
__global__ __launch_bounds__(256) void gemm_fused3(
    const unsigned short* __restrict__ A, const unsigned short* __restrict__ Bt,
    unsigned short* __restrict__ Cq, unsigned short* __restrict__ Ck,
    unsigned short* __restrict__ Cc, int K) {
  __shared__ unsigned short As[1024 * 8];
  __shared__ unsigned short Bs[1024 * 8];
  const int tid = threadIdx.x;
  const int m0 = blockIdx.y * 128, n0 = blockIdx.x * 128;
  const int wave = tid >> 6, lane = tid & 63;
  const int wm = (wave >> 1) * 64, wn = (wave & 1) * 64;
  const int l16 = lane & 15, quad = lane >> 4;

  f32x4 acc[4][4];
#pragma unroll
  for (int i = 0; i < 4; ++i)
#pragma unroll
    for (int j = 0; j < 4; ++j)
#pragma unroll
      for (int r = 0; r < 4; ++r) acc[i][j][r] = 0.f;

  for (int k0 = 0; k0 < K; k0 += 64) {
    __syncthreads();
#pragma unroll
    for (int it = 0; it < 4; ++it) {
      int c = it * 256 + tid;
      int m = c >> 3, kc = (c & 7) ^ (m & 7);
      g2lds16(&A[(size_t)(m0 + m) * K + k0 + kc * 8], &As[c * 8]);
    }
#pragma unroll
    for (int it = 0; it < 4; ++it) {
      int c = it * 256 + tid;
      int n = c >> 3, kc = (c & 7) ^ (n & 7);
      g2lds16(&Bt[(size_t)(n0 + n) * K + k0 + kc * 8], &Bs[c * 8]);
    }
    __syncthreads();

#pragma unroll
    for (int ks = 0; ks < 2; ++ks) {
      bf16x8 af[4], bfr[4];
#pragma unroll
      for (int mi = 0; mi < 4; ++mi) {
        int m = wm + mi * 16 + l16;
        af[mi] = *reinterpret_cast<const bf16x8*>(
            &As[(m * 8 + ((ks * 4 + quad) ^ (m & 7))) * 8]);
      }
#pragma unroll
      for (int ni = 0; ni < 4; ++ni) {
        int n = wn + ni * 16 + l16;
        bfr[ni] = *reinterpret_cast<const bf16x8*>(
            &Bs[(n * 8 + ((ks * 4 + quad) ^ (n & 7))) * 8]);
      }
#pragma unroll
      for (int mi = 0; mi < 4; ++mi)
#pragma unroll
        for (int ni = 0; ni < 4; ++ni)
          acc[mi][ni] = __builtin_amdgcn_mfma_f32_16x16x32_bf16(
              af[mi], bfr[ni], acc[mi][ni], 0, 0, 0);
    }
  }

  unsigned short* dst;
  int w, cb;
  if (n0 < 1024)      { dst = Cq; w = 1024; cb = 0; }
  else if (n0 < 2048) { dst = Ck; w = 1024; cb = 1024; }
  else                { dst = Cc; w = 128;  cb = 2048; }
#pragma unroll
  for (int mi = 0; mi < 4; ++mi)
#pragma unroll
    for (int ni = 0; ni < 4; ++ni) {
      int row = m0 + wm + mi * 16 + quad * 4;
      int col = n0 - cb + wn + ni * 16 + l16;
#pragma unroll
      for (int r = 0; r < 4; ++r)
        dst[(size_t)(row + r) * w + col] = f2b(acc[mi][ni][r]);
    }
}

// ------- fused GEMM #2: [k_c(acc->ksb) | v_c] = ckv @ [wkc|wvc]^T -------
__global__ __launch_bounds__(256) void gemm_fused2(
    const unsigned short* __restrict__ A, const unsigned short* __restrict__ Bt,
    unsigned short* __restrict__ Ck, unsigned short* __restrict__ Cv, int K) {
  __shared__ unsigned short As[1024 * 8];
  __shared__ unsigned short Bs[1024 * 8];
  const int tid = threadIdx.x;
  const int m0 = blockIdx.y * 128, n0 = blockIdx.x * 128;
  const int wave = tid >> 6, lane = tid & 63;
  const int wm = (wave >> 1) * 64, wn = (wave & 1) * 64;
  const int l16 = lane & 15, quad = lane >> 4;

  f32x4 acc[4][4];
#pragma unroll
  for (int i = 0; i < 4; ++i)
#pragma unroll
    for (int j = 0; j < 4; ++j)
#pragma unroll
      for (int r = 0; r < 4; ++r) acc[i][j][r] = 0.f;

  for (int k0 = 0; k0 < K; k0 += 64) {
    __syncthreads();
#pragma unroll
    for (int it = 0; it < 4; ++it) {
      int c = it * 256 + tid;
      int m = c >> 3, kc = (c & 7) ^ (m & 7);
      g2lds16(&A[(size_t)(m0 + m) * K + k0 + kc * 8], &As[c * 8]);
    }
#pragma unroll
    for (int it = 0; it < 4; ++it) {
      int c = it * 256 + tid;
      int n = c >> 3, kc = (c & 7) ^ (n & 7);
      g2lds16(&Bt[(size_t)(n0 + n) * K + k0 + kc * 8], &Bs[c * 8]);
    }
    __syncthreads();

#pragma unroll
    for (int ks = 0; ks < 2; ++ks) {
      bf16x8 af[4], bfr[4];
#pragma unroll
      for (int mi = 0; mi < 4; ++mi) {
        int m = wm + mi * 16 + l16;
        af[mi] = *reinterpret_cast<const bf16x8*>(
            &As[(m * 8 + ((ks * 4 + quad) ^ (m & 7))) * 8]);
      }
#pragma unroll
      for (int ni = 0; ni < 4; ++ni) {
        int n = wn + ni * 16 + l16;
        bfr[ni] = *reinterpret_cast<const bf16x8*>(
            &Bs[(n * 8 + ((ks * 4 + quad) ^ (n & 7))) * 8]);
      }
#pragma unroll
      for (int mi = 0; mi < 4; ++mi)
#pragma unroll
        for (int ni = 0; ni < 4; ++ni)
          acc[mi][ni] = __builtin_amdgcn_mfma_f32_16x16x32_bf16(
              af[mi], bfr[ni], acc[mi][ni], 0, 0, 0);
    }
  }

  const bool first = (n0 < 1024);
  unsigned short* dst = first ? Ck : Cv;
  int cb = first ? 0 : 1024;
#pragma unroll
  for (int mi = 0; mi < 4; ++mi)
#pragma unroll
    for (int ni = 0; ni < 4; ++ni) {
      int row = m0 + wm + mi * 16 + quad * 4;
      int col = n0 - cb + wn + ni * 16 + l16;
#pragma unroll
      for (int r = 0; r < 4; ++r) {
        size_t idx = (size_t)(row + r) * 1024 + col;
        float val = acc[mi][ni][r];
        if (first) val += b2f(dst[idx]);   // accumulate onto rope'd k_r
        dst[idx] = f2b(val);
      }
    }
}

// ---------------- fused rope transform (in place) ----------------
__global__ void rope_kernel(unsigned short* __restrict__ qr,
                            unsigned short* __restrict__ kr,
                            const float* __restrict__ tq,
                            const float* __restrict__ tk) {
  int idx = blockIdx.x * 256 + threadIdx.x;
  int i = idx & 31;
  int mh = idx >> 5;       // m*16 + h
  int m = mh >> 4;
  float f = exp2f(-(float)i * (13.287712379549449f / 32.f));  // 10000^(-i/32)
  float cq = cosf(tq[m] * f);
  float ck = cosf(tk[m] * f);
  size_t base = (size_t)mh * 64;
  float q1 = b2f(qr[base + i]), q2 = b2f(qr[base + i + 32]);
  float k1 = b2f(kr[base + i]), k2 = b2f(kr[base + i + 32]);
  qr[base + i]      = f2b((q1 * cq - q2 * ck) * 0.125f);
  qr[base + i + 32] = f2b((q2 * cq + q1 * ck) * 0.125f);
  kr[base + i]      = f2b(k1 * cq - k2 * ck);
  kr[base + i + 32] = f2b(k2 * cq + k1 * ck);
}

// ---------------- V transpose: [b,l,h,d] -> Vt[b,h,d,l] ----------------
__global__ __launch_bounds__(256) void vtrans_kernel(
    const unsigned short* __restrict__ v, unsigned short* __restrict__ vt,
    int L) {
  __shared__ unsigned short T[64 * 72];
  const int tid = threadIdx.x;
  const int l0 = blockIdx.x * 64, bh = blockIdx.y;
  const size_t inbase = ((size_t)(bh >> 4) * L) * 1024 + (bh & 15) * 64;
  const size_t outbase = (size_t)bh * 64 * L;
#pragma unroll
  for (int it = 0; it < 2; ++it) {
    int c = tid + it * 256;               // [0,512)
    int l = c >> 3, dc = c & 7;
    ushort8v x = *reinterpret_cast<const ushort8v*>(
        &v[inbase + (size_t)(l0 + l) * 1024 + dc * 8]);
    *reinterpret_cast<ushort8v*>(&T[l * 72 + dc * 8]) = x;
  }
  __syncthreads();
#pragma unroll
  for (int it = 0; it < 2; ++it) {
    int c = tid + it * 256;
    int d = c >> 3, lc = c & 7;
    ushort8v y;
#pragma unroll
    for (int j = 0; j < 8; ++j) y[j] = T[(lc * 8 + j) * 72 + d];
    *reinterpret_cast<ushort8v*>(&vt[outbase + (size_t)d * L + l0 + lc * 8]) = y;
  }
}

// ---------- flash v7: transposed 32x32 MFMA, hardened sync, no alias -----
// grid (L/64, B*H), block 128 = 2 waves x 32 q. S^T = K Q^T, O^T = V^T P^T;
// packed b64 P stores, denominator in registers. dbuf K/V staging.
// Same-wave LDS RAW protected by explicit s_waitcnt lgkmcnt(0).
__global__ __launch_bounds__(128) void flash7_kernel(
    const unsigned short* __restrict__ qs, const unsigned short* __restrict__ ks,
    const unsigned short* __restrict__ vt, unsigned short* __restrict__ o,
    int L) {
  __shared__ unsigned short Ks[2][512 * 8];  // [key][d] swizzled 16B chunks
  __shared__ unsigned short Vs[2][512 * 8];  // [d][key] swizzled
  __shared__ unsigned short Ps[2][32 * 68];  // per-wave [q][key], pitch 68
  const int tid = threadIdx.x;
  const int wave = tid >> 6, lane = tid & 63;
  const int q32 = lane & 31, half = lane >> 5;
  const int bh = blockIdx.y;                 // b*16 + h
  const int qb = blockIdx.x * 64 + wave * 32;
  const size_t base = ((size_t)(bh >> 4) * L) * 1024 + (bh & 15) * 64;
  const size_t vtbase = (size_t)bh * 64 * L;

  // Q as B-fragments (n=lane&31=q, k=(lane>>5)*8+j), 4 d-chunks of 16
  bf16x8 qf[4];
#pragma unroll
  for (int c = 0; c < 4; ++c)
    qf[c] = *reinterpret_cast<const bf16x8*>(
        &qs[base + (size_t)(qb + q32) * 1024 + c * 16 + half * 8]);

  f32x16 ot[2];
#pragma unroll
  for (int dt = 0; dt < 2; ++dt)
#pragma unroll
    for (int r = 0; r < 16; ++r) ot[dt][r] = 0.f;
  float lacc = 0.f;

  const int T = L / 64;
  // prologue: stage tile 0
#pragma unroll
  for (int it = 0; it < 4; ++it) {
    int c = it * 128 + tid;
    int key = c >> 3, dc = (c & 7) ^ (key & 7);
    g2lds16(&ks[base + (size_t)key * 1024 + dc * 8], &Ks[0][c * 8]);
  }
#pragma unroll
  for (int it = 0; it < 4; ++it) {
    int c = it * 128 + tid;
    int d = c >> 3, kc = (c & 7) ^ (d & 7);
    g2lds16(&vt[vtbase + (size_t)d * L + kc * 8], &Vs[0][c * 8]);
  }

  for (int t = 0; t < T; ++t) {
    __syncthreads();   // drains stage(t) vmcnt + all prior LDS ops
    if (t + 1 < T) {
      int k0 = (t + 1) * 64, nb = (t + 1) & 1;
#pragma unroll
      for (int it = 0; it < 4; ++it) {
        int c = it * 128 + tid;
        int key = c >> 3, dc = (c & 7) ^ (key & 7);
        g2lds16(&ks[base + (size_t)(k0 + key) * 1024 + dc * 8], &Ks[nb][c * 8]);
      }
#pragma unroll
      for (int it = 0; it < 4; ++it) {
        int c = it * 128 + tid;
        int d = c >> 3, kc = (c & 7) ^ (d & 7);
        g2lds16(&vt[vtbase + (size_t)d * L + k0 + kc * 8], &Vs[nb][c * 8]);
      }
    }
    const int cb = t & 1;

    // S^T[key][q]: A = K (m=key), B = Q (n=q); 2 key-tiles of 32
    f32x16 s[2];
#pragma unroll
    for (int kt = 0; kt < 2; ++kt) {
      f32x16 z;
#pragma unroll
      for (int r = 0; r < 16; ++r) z[r] = 0.f;
      const int key = kt * 32 + q32;
#pragma unroll
      for (int c = 0; c < 4; ++c) {
        int dc = (2 * c + half) ^ (key & 7);
        bf16x8 ak = *reinterpret_cast<const bf16x8*>(
            &Ks[cb][(key * 8 + dc) * 8]);
        z = __builtin_amdgcn_mfma_f32_32x32x16_bf16(ak, qf[c], z, 0, 0, 0);
      }
      s[kt] = z;
    }

    lds_fence();   // prior P reads (pf, last tile) complete before rewrite
    // exp + l accum + packed b64 stores: reg group 4g..4g+3 = 4 consec keys
#pragma unroll
    for (int kt = 0; kt < 2; ++kt)
#pragma unroll
      for (int g = 0; g < 4; ++g) {
        float e0 = __expf(s[kt][4 * g + 0]);
        float e1 = __expf(s[kt][4 * g + 1]);
        float e2 = __expf(s[kt][4 * g + 2]);
        float e3 = __expf(s[kt][4 * g + 3]);
        lacc += (e0 + e1) + (e2 + e3);
        ushort4v pk;
        pk[0] = f2b(e0); pk[1] = f2b(e1); pk[2] = f2b(e2); pk[3] = f2b(e3);
        int key = kt * 32 + g * 8 + half * 4;
        *reinterpret_cast<ushort4v*>(&Ps[wave][q32 * 68 + key]) = pk;
      }
    lds_fence();   // P writes complete before cross-lane read

    // O^T[d][q] += V^T x P^T: A = Vt (m=d), B = P (n=q, k=key contiguous)
    bf16x8 pf[4];
#pragma unroll
    for (int c = 0; c < 4; ++c) {
      int off = q32 * 68 + c * 16 + half * 8;
      ushort4v lo = *reinterpret_cast<const ushort4v*>(&Ps[wave][off]);
      ushort4v hi = *reinterpret_cast<const ushort4v*>(&Ps[wave][off + 4]);
      ushort8v u;
      u[0] = lo[0]; u[1] = lo[1]; u[2] = lo[2]; u[3] = lo[3];
      u[4] = hi[0]; u[5] = hi[1]; u[6] = hi[2]; u[7] = hi[3];
      pf[c] = *reinterpret_cast<bf16x8*>(&u);
    }
#pragma unroll
    for (int dt = 0; dt < 2; ++dt) {
      const int d = dt * 32 + q32;
#pragma unroll
      for (int c = 0; c < 4; ++c) {
        int kc = (2 * c + half) ^ (d & 7);
        bf16x8 av = *reinterpret_cast<const bf16x8*>(
            &Vs[cb][(d * 8 + kc) * 8]);
        ot[dt] = __builtin_amdgcn_mfma_f32_32x32x16_bf16(av, pf[c], ot[dt],
                                                         0, 0, 0);
      }
    }
  }

  // l: this lane covered half the keys for q=q32; other half is lane^32
  lacc += __shfl_xor(lacc, 32, 64);
  float linv = 1.f / lacc;

  // normalize in regs, stage O rows in Ps (reuse), coalesced global write
  lds_fence();   // last-tile pf reads complete before Ps reuse
#pragma unroll
  for (int dt = 0; dt < 2; ++dt)
#pragma unroll
    for (int g = 0; g < 4; ++g) {
      ushort4v pk;
      pk[0] = f2b(ot[dt][4 * g + 0] * linv);
      pk[1] = f2b(ot[dt][4 * g + 1] * linv);
      pk[2] = f2b(ot[dt][4 * g + 2] * linv);
      pk[3] = f2b(ot[dt][4 * g + 3] * linv);
      int d = dt * 32 + g * 8 + half * 4;
      *reinterpret_cast<ushort4v*>(&Ps[wave][q32 * 68 + d]) = pk;
    }
  lds_fence();   // O staging visible before cross-lane read
#pragma unroll
  for (int it = 0; it < 4; ++it) {
    int q = it * 8 + (lane >> 3);
    int d8 = (lane & 7) * 8;
    ushort4v lo = *reinterpret_cast<const ushort4v*>(&Ps[wave][q * 68 + d8]);
    ushort4v hi = *reinterpret_cast<const ushort4v*>(&Ps[wave][q * 68 + d8 + 4]);
    ushort8v row;
    row[0] = lo[0]; row[1] = lo[1]; row[2] = lo[2]; row[3] = lo[3];
    row[4] = hi[0]; row[5] = hi[1]; row[6] = hi[2]; row[7] = hi[3];
    *reinterpret_cast<ushort8v*>(
        &o[base + (size_t)(qb + q) * 1024 + d8]) = row;
  }
}

// ---------------- driver ----------------
extern "C" void kernel_launch(void* const* d_in, const int* in_sizes, int n_in,
                              void* d_out, int out_size, void* d_ws, size_t ws_size,
                              hipStream_t stream) {
  const float* X    = (const float*)d_in[0];
  const float* tq   = (const float*)d_in[1];
  const float* tk   = (const float*)d_in[2];
  const float* wkvc = (const float*)d_in[3];
  const float* wkc  = (const float*)d_in[4];
  const float* wvc  = (const float*)d_in[5];
  const float* wqr  = (const float*)d_in[6];
  const float* wkr  = (const float*)d_in[7];
  const float* wo   = (const float*)d_in[8];

  const int D = 1024, DC = 128, L = 2048;
  const int M = in_sizes[0] / D;       // B*L
  const int B = M / L;
  const int NBH = B * 16;
  (void)n_in; (void)out_size; (void)ws_size;

  unsigned short* p = (unsigned short*)d_ws;
  auto take = [&](size_t n) { unsigned short* r = p; p += n; return r; };
  unsigned short* Xb    = take((size_t)M * D);
  unsigned short* qsb   = take((size_t)M * D);
  unsigned short* ksb   = take((size_t)M * D);
  unsigned short* vcb   = take((size_t)M * D);
  unsigned short* ckv   = take((size_t)M * DC);
  unsigned short* Wbig  = take((size_t)(2 * D + DC) * D);   // [wqr|wkr|wkvc]^T
  unsigned short* Wkcvc = take((size_t)(2 * D) * DC);       // [wkc|wvc]^T
  unsigned short* WoT   = take((size_t)D * D);
  unsigned short* vtb   = Xb;   // Xb dead after fused3 gemm
  unsigned short* obuf  = vcb;  // vcb dead after vtrans; flash O lands here

  // prep
  cvt_kernel<<<(M * D / 8 + 255) / 256, 256, 0, stream>>>(X, Xb, M * D / 8);
  auto wt = [&](const float* W, unsigned short* WT, int K, int N) {
    dim3 g(N / 64, K / 64);
    wtrans_kernel<<<g, 256, 0, stream>>>(W, WT, K, N);
  };
  wt(wqr,  Wbig,                          D, D);
  wt(wkr,  Wbig + (size_t)D * D,          D, D);
  wt(wkvc, Wbig + (size_t)2 * D * D,      D, DC);
  wt(wkc,  Wkcvc,                         DC, D);
  wt(wvc,  Wkcvc + (size_t)D * DC,        DC, D);
  wt(wo,   WoT,                           D, D);

  {
    dim3 g((2 * D + DC) / 128, M / 128);                   // (17, 32)
    gemm_fused3<<<g, 256, 0, stream>>>(Xb, Wbig, qsb, ksb, ckv, D);
  }
  rope_kernel<<<(M * 512) / 256, 256, 0, stream>>>(qsb, ksb, tq, tk);
  {
    dim3 g(2 * D / 128, M / 128);                          // (16, 32)
    gemm_fused2<<<g, 256, 0, stream>>>(ckv, Wkcvc, ksb, vcb, DC);
  }

  dim3 tg(L / 64, NBH);
  vtrans_kernel<<<tg, 256, 0, stream>>>(vcb, vtb, L);

  dim3 fg(L / 64, NBH);                                    // (32, 32)
  flash7_kernel<<<fg, 128, 0, stream>>>(qsb, ksb, vtb, obuf, L);

  {
    dim3 g(D / 128, M / 64);                               // (8, 64)
    gemm_bt<64, float, false><<<g, 256, 0, stream>>>(
        obuf, WoT, (float*)d_out, M, D, D);
  }
}

// Round 11
// 246.925 us; speedup vs baseline: 1.1182x; 1.1182x over previous
//
#include <hip/hip_runtime.h>

typedef float          f32x4    __attribute__((ext_vector_type(4)));
typedef float          float8v  __attribute__((ext_vector_type(8)));
typedef unsigned short ushort8v __attribute__((ext_vector_type(8)));
typedef __bf16         bf16x8   __attribute__((ext_vector_type(8)));

__device__ __forceinline__ unsigned short f2b(float x) {
  union { __bf16 b; unsigned short u; } v;
  v.b = (__bf16)x;                       // hw v_cvt (RNE) on gfx950
  return v.u;
}
__device__ __forceinline__ float b2f(unsigned short h) {
  union { unsigned u; float f; } v; v.u = ((unsigned)h) << 16;
  return v.f;
}
// drain this wave's LDS ops without touching vmcnt (prefetch stays in flight)
__device__ __forceinline__ void lds_fence() {
  __builtin_amdgcn_wave_barrier();
  asm volatile("s_waitcnt lgkmcnt(0)" ::: "memory");
}

// async global->LDS, 16B per lane; LDS dest = wave-uniform base + lane*16
__device__ __forceinline__ void g2lds16(const unsigned short* g,
                                        unsigned short* l) {
  __builtin_amdgcn_global_load_lds(
      (const __attribute__((address_space(1))) unsigned int*)g,
      (__attribute__((address_space(3))) unsigned int*)l, 16, 0, 0);
}

// ---------------- f32 -> bf16 convert, 8 elems/thread ----------------
__global__ void cvt_kernel(const float* __restrict__ src,
                           unsigned short* __restrict__ dst, int n8) {
  int i = blockIdx.x * 256 + threadIdx.x;
  if (i >= n8) return;
  float8v v = reinterpret_cast<const float8v*>(src)[i];
  ushort8v h;
#pragma unroll
  for (int j = 0; j < 8; ++j) h[j] = f2b(v[j]);
  reinterpret_cast<ushort8v*>(dst)[i] = h;
}

// -------- weight transpose+convert: W(f32)[K][N] -> WT(bf16)[N][K] --------
__global__ __launch_bounds__(256) void wtrans_kernel(
    const float* __restrict__ W, unsigned short* __restrict__ WT,
    int K, int N) {
  __shared__ unsigned short T[64 * 72];
  const int tid = threadIdx.x;
  const int n0 = blockIdx.x * 64, k0 = blockIdx.y * 64;
#pragma unroll
  for (int it = 0; it < 2; ++it) {
    int c = tid + it * 256;               // [0,512)
    int r = c >> 3, cc = c & 7;
    float8v v = *reinterpret_cast<const float8v*>(
        &W[(size_t)(k0 + r) * N + n0 + cc * 8]);
    ushort8v h;
#pragma unroll
    for (int j = 0; j < 8; ++j) h[j] = f2b(v[j]);
    *reinterpret_cast<ushort8v*>(&T[r * 72 + cc * 8]) = h;
  }
  __syncthreads();
#pragma unroll
  for (int it = 0; it < 2; ++it) {
    int c = tid + it * 256;
    int n = c >> 3, kc = c & 7;
    ushort8v y;
#pragma unroll
    for (int j = 0; j < 8; ++j) y[j] = T[(kc * 8 + j) * 72 + n];
    *reinterpret_cast<ushort8v*>(&WT[(size_t)(n0 + n) * K + k0 + kc * 8]) = y;
  }
}

// ---------------- generic gemm_bt (single-buffer) ----------------
template <int TM, typename CT, bool ACC>
__global__ __launch_bounds__(256) void gemm_bt(
    const unsigned short* __restrict__ A, const unsigned short* __restrict__ Bt,
    CT* __restrict__ C, int M, int N, int K) {
  __shared__ unsigned short As[TM * 64];
  __shared__ unsigned short Bs[128 * 64];
  const int tid = threadIdx.x;
  const int m0 = blockIdx.y * TM, n0 = blockIdx.x * 128;
  const int wave = tid >> 6, lane = tid & 63;
  const int wm = (wave >> 1) * (TM / 2), wn = (wave & 1) * 64;
  const int l16 = lane & 15, quad = lane >> 4;
  constexpr int MI = TM / 32;

  f32x4 acc[MI][4];
#pragma unroll
  for (int i = 0; i < MI; ++i)
#pragma unroll
    for (int j = 0; j < 4; ++j)
#pragma unroll
      for (int r = 0; r < 4; ++r) acc[i][j][r] = 0.f;

  for (int k0 = 0; k0 < K; k0 += 64) {
    __syncthreads();
#pragma unroll
    for (int it = 0; it < TM * 8 / 256; ++it) {
      int c = it * 256 + tid;
      int m = c >> 3, kc = (c & 7) ^ (m & 7);
      g2lds16(&A[(size_t)(m0 + m) * K + k0 + kc * 8], &As[c * 8]);
    }
#pragma unroll
    for (int it = 0; it < 4; ++it) {
      int c = it * 256 + tid;
      int n = c >> 3, kc = (c & 7) ^ (n & 7);
      g2lds16(&Bt[(size_t)(n0 + n) * K + k0 + kc * 8], &Bs[c * 8]);
    }
    __syncthreads();

#pragma unroll
    for (int ks = 0; ks < 2; ++ks) {
      bf16x8 af[MI], bfr[4];
#pragma unroll
      for (int mi = 0; mi < MI; ++mi) {
        int m = wm + mi * 16 + l16;
        af[mi] = *reinterpret_cast<const bf16x8*>(
            &As[(m * 8 + ((ks * 4 + quad) ^ (m & 7))) * 8]);
      }
#pragma unroll
      for (int ni = 0; ni < 4; ++ni) {
        int n = wn + ni * 16 + l16;
        bfr[ni] = *reinterpret_cast<const bf16x8*>(
            &Bs[(n * 8 + ((ks * 4 + quad) ^ (n & 7))) * 8]);
      }
#pragma unroll
      for (int mi = 0; mi < MI; ++mi)
#pragma unroll
        for (int ni = 0; ni < 4; ++ni)
          acc[mi][ni] = __builtin_amdgcn_mfma_f32_16x16x32_bf16(
              af[mi], bfr[ni], acc[mi][ni], 0, 0, 0);
    }
  }

#pragma unroll
  for (int mi = 0; mi < MI; ++mi)
#pragma unroll
    for (int ni = 0; ni < 4; ++ni) {
      int row = m0 + wm + mi * 16 + quad * 4;
      int col = n0 + wn + ni * 16 + l16;
#pragma unroll
      for (int r = 0; r < 4; ++r) {
        size_t idx = (size_t)(row + r) * N + col;
        float val = acc[mi][ni][r];
        if constexpr (sizeof(CT) == 2) {
          if constexpr (ACC) val += b2f(C[idx]);
          C[idx] = f2b(val);
        } else {
          if constexpr (ACC) val += C[idx];
          C[idx] = val;
        }
      }
    }
}

// ------- fused GEMM #1: [q_r | k_r | c_kv] = X @ [wqr|wkr|wkvc]^T -------
__global__ __launch_bounds__(256) void gemm_fused3(
    const unsigned short* __restrict__ A, const unsigned short* __restrict__ Bt,
    unsigned short* __restrict__ Cq, unsigned short* __restrict__ Ck,
    unsigned short* __restrict__ Cc, int K) {
  __shared__ unsigned short As[1024 * 8];
  __shared__ unsigned short Bs[1024 * 8];
  const int tid = threadIdx.x;
  const int m0 = blockIdx.y * 128, n0 = blockIdx.x * 128;
  const int wave = tid >> 6, lane = tid & 63;
  const int wm = (wave >> 1) * 64, wn = (wave & 1) * 64;
  const int l16 = lane & 15, quad = lane >> 4;

  f32x4 acc[4][4];
#pragma unroll
  for (int i = 0; i < 4; ++i)
#pragma unroll
    for (int j = 0; j < 4; ++j)
#pragma unroll
      for (int r = 0; r < 4; ++r) acc[i][j][r] = 0.f;

  for (int k0 = 0; k0 < K; k0 += 64) {
    __syncthreads();
#pragma unroll
    for (int it = 0; it < 4; ++it) {
      int c = it * 256 + tid;
      int m = c >> 3, kc = (c & 7) ^ (m & 7);
      g2lds16(&A[(size_t)(m0 + m) * K + k0 + kc * 8], &As[c * 8]);
    }
#pragma unroll
    for (int it = 0; it < 4; ++it) {
      int c = it * 256 + tid;
      int n = c >> 3, kc = (c & 7) ^ (n & 7);
      g2lds16(&Bt[(size_t)(n0 + n) * K + k0 + kc * 8], &Bs[c * 8]);
    }
    __syncthreads();

#pragma unroll
    for (int ks = 0; ks < 2; ++ks) {
      bf16x8 af[4], bfr[4];
#pragma unroll
      for (int mi = 0; mi < 4; ++mi) {
        int m = wm + mi * 16 + l16;
        af[mi] = *reinterpret_cast<const bf16x8*>(
            &As[(m * 8 + ((ks * 4 + quad) ^ (m & 7))) * 8]);
      }
#pragma unroll
      for (int ni = 0; ni < 4; ++ni) {
        int n = wn + ni * 16 + l16;
        bfr[ni] = *reinterpret_cast<const bf16x8*>(
            &Bs[(n * 8 + ((ks * 4 + quad) ^ (n & 7))) * 8]);
      }
#pragma unroll
      for (int mi = 0; mi < 4; ++mi)
#pragma unroll
        for (int ni = 0; ni < 4; ++ni)
          acc[mi][ni] = __builtin_amdgcn_mfma_f32_16x16x32_bf16(
              af[mi], bfr[ni], acc[mi][ni], 0, 0, 0);
    }
  }

  unsigned short* dst;
  int w, cb;
  if (n0 < 1024)      { dst = Cq; w = 1024; cb = 0; }
  else if (n0 < 2048) { dst = Ck; w = 1024; cb = 1024; }
  else                { dst = Cc; w = 128;  cb = 2048; }
#pragma unroll
  for (int mi = 0; mi < 4; ++mi)
#pragma unroll
    for (int ni = 0; ni < 4; ++ni) {
      int row = m0 + wm + mi * 16 + quad * 4;
      int col = n0 - cb + wn + ni * 16 + l16;
#pragma unroll
      for (int r = 0; r < 4; ++r)
        dst[(size_t)(row + r) * w + col] = f2b(acc[mi][ni][r]);
    }
}

// ------- fused GEMM #2: [k_c(acc->ksb) | v_c] = ckv @ [wkc|wvc]^T -------
__global__ __launch_bounds__(256) void gemm_fused2(
    const unsigned short* __restrict__ A, const unsigned short* __restrict__ Bt,
    unsigned short* __restrict__ Ck, unsigned short* __restrict__ Cv, int K) {
  __shared__ unsigned short As[1024 * 8];
  __shared__ unsigned short Bs[1024 * 8];
  const int tid = threadIdx.x;
  const int m0 = blockIdx.y * 128, n0 = blockIdx.x * 128;
  const int wave = tid >> 6, lane = tid & 63;
  const int wm = (wave >> 1) * 64, wn = (wave & 1) * 64;
  const int l16 = lane & 15, quad = lane >> 4;

  f32x4 acc[4][4];
#pragma unroll
  for (int i = 0; i < 4; ++i)
#pragma unroll
    for (int j = 0; j < 4; ++j)
#pragma unroll
      for (int r = 0; r < 4; ++r) acc[i][j][r] = 0.f;

  for (int k0 = 0; k0 < K; k0 += 64) {
    __syncthreads();
#pragma unroll
    for (int it = 0; it < 4; ++it) {
      int c = it * 256 + tid;
      int m = c >> 3, kc = (c & 7) ^ (m & 7);
      g2lds16(&A[(size_t)(m0 + m) * K + k0 + kc * 8], &As[c * 8]);
    }
#pragma unroll
    for (int it = 0; it < 4; ++it) {
      int c = it * 256 + tid;
      int n = c >> 3, kc = (c & 7) ^ (n & 7);
      g2lds16(&Bt[(size_t)(n0 + n) * K + k0 + kc * 8], &Bs[c * 8]);
    }
    __syncthreads();

#pragma unroll
    for (int ks = 0; ks < 2; ++ks) {
      bf16x8 af[4], bfr[4];
#pragma unroll
      for (int mi = 0; mi < 4; ++mi) {
        int m = wm + mi * 16 + l16;
        af[mi] = *reinterpret_cast<const bf16x8*>(
            &As[(m * 8 + ((ks * 4 + quad) ^ (m & 7))) * 8]);
      }
#pragma unroll
      for (int ni = 0; ni < 4; ++ni) {
        int n = wn + ni * 16 + l16;
        bfr[ni] = *reinterpret_cast<const bf16x8*>(
            &Bs[(n * 8 + ((ks * 4 + quad) ^ (n & 7))) * 8]);
      }
#pragma unroll
      for (int mi = 0; mi < 4; ++mi)
#pragma unroll
        for (int ni = 0; ni < 4; ++ni)
          acc[mi][ni] = __builtin_amdgcn_mfma_f32_16x16x32_bf16(
              af[mi], bfr[ni], acc[mi][ni], 0, 0, 0);
    }
  }

  const bool first = (n0 < 1024);
  unsigned short* dst = first ? Ck : Cv;
  int cb = first ? 0 : 1024;
#pragma unroll
  for (int mi = 0; mi < 4; ++mi)
#pragma unroll
    for (int ni = 0; ni < 4; ++ni) {
      int row = m0 + wm + mi * 16 + quad * 4;
      int col = n0 - cb + wn + ni * 16 + l16;
#pragma unroll
      for (int r = 0; r < 4; ++r) {
        size_t idx = (size_t)(row + r) * 1024 + col;
        float val = acc[mi][ni][r];
        if (first) val += b2f(dst[idx]);   // accumulate onto rope'd k_r
        dst[idx] = f2b(val);
      }
    }
}

// ---------------- fused rope transform (in place) ----------------
__global__ void rope_kernel(unsigned short* __restrict__ qr,
                            unsigned short* __restrict__ kr,
                            const float* __restrict__ tq,
                            const float* __restrict__ tk) {
  int idx = blockIdx.x * 256 + threadIdx.x;
  int i = idx & 31;
  int mh = idx >> 5;       // m*16 + h
  int m = mh >> 4;
  float f = exp2f(-(float)i * (13.287712379549449f / 32.f));  // 10000^(-i/32)
  float cq = cosf(tq[m] * f);
  float ck = cosf(tk[m] * f);
  size_t base = (size_t)mh * 64;
  float q1 = b2f(qr[base + i]), q2 = b2f(qr[base + i + 32]);
  float k1 = b2f(kr[base + i]), k2 = b2f(kr[base + i + 32]);
  qr[base + i]      = f2b((q1 * cq - q2 * ck) * 0.125f);
  qr[base + i + 32] = f2b((q2 * cq + q1 * ck) * 0.125f);
  kr[base + i]      = f2b(k1 * cq - k2 * ck);
  kr[base + i + 32] = f2b(k2 * cq + k1 * ck);
}

// ---------------- V transpose: [b,l,h,d] -> Vt[b,h,d,l] ----------------
__global__ __launch_bounds__(256) void vtrans_kernel(
    const unsigned short* __restrict__ v, unsigned short* __restrict__ vt,
    int L) {
  __shared__ unsigned short T[64 * 72];
  const int tid = threadIdx.x;
  const int l0 = blockIdx.x * 64, bh = blockIdx.y;
  const size_t inbase = ((size_t)(bh >> 4) * L) * 1024 + (bh & 15) * 64;
  const size_t outbase = (size_t)bh * 64 * L;
#pragma unroll
  for (int it = 0; it < 2; ++it) {
    int c = tid + it * 256;               // [0,512)
    int l = c >> 3, dc = c & 7;
    ushort8v x = *reinterpret_cast<const ushort8v*>(
        &v[inbase + (size_t)(l0 + l) * 1024 + dc * 8]);
    *reinterpret_cast<ushort8v*>(&T[l * 72 + dc * 8]) = x;
  }
  __syncthreads();
#pragma unroll
  for (int it = 0; it < 2; ++it) {
    int c = tid + it * 256;
    int d = c >> 3, lc = c & 7;
    ushort8v y;
#pragma unroll
    for (int j = 0; j < 8; ++j) y[j] = T[(lc * 8 + j) * 72 + d];
    *reinterpret_cast<ushort8v*>(&vt[outbase + (size_t)d * L + l0 + lc * 8]) = y;
  }
}

// ---------- flash v8: flash5 (r8, stable) + K-fragment read hoist ----------
// grid (L/64, B*H), block 128 = 2 waves x 32 q. dbuf K/V staging, 1
// __syncthreads/tile. K fragments read ONCE and reused across both m-tiles
// (halves the dominant LDS-read term). No max-subtraction (|s| bounded).
__global__ __launch_bounds__(128) void flash8_kernel(
    const unsigned short* __restrict__ qs, const unsigned short* __restrict__ ks,
    const unsigned short* __restrict__ vt, unsigned short* __restrict__ o,
    int L) {
  __shared__ unsigned short Ks[2][512 * 8];  // 64 key x 64 d, swizzled
  __shared__ unsigned short Vs[2][512 * 8];  // 64 d x 64 key, swizzled
  __shared__ unsigned short Ps[2][16 * 72];  // per-wave P, reused per m-tile
  const int tid = threadIdx.x;
  const int wave = tid >> 6, lane = tid & 63;
  const int l16 = lane & 15, quad = lane >> 4;
  const int bh = blockIdx.y;                 // b*16 + h
  const int qb = blockIdx.x * 64 + wave * 32;
  const size_t base = ((size_t)(bh >> 4) * L) * 1024 + (bh & 15) * 64;
  const size_t vtbase = (size_t)bh * 64 * L;

  bf16x8 aq[2][2];
#pragma unroll
  for (int mt = 0; mt < 2; ++mt) {
    size_t qrow = base + (size_t)(qb + mt * 16 + l16) * 1024;
    aq[mt][0] = *reinterpret_cast<const bf16x8*>(&qs[qrow + quad * 8]);
    aq[mt][1] = *reinterpret_cast<const bf16x8*>(&qs[qrow + 32 + quad * 8]);
  }

  ushort8v onesu;
#pragma unroll
  for (int j = 0; j < 8; ++j) onesu[j] = 0x3F80;  // bf16 1.0
  bf16x8 ones = *reinterpret_cast<bf16x8*>(&onesu);

  f32x4 oacc[2][4];
  f32x4 lacc[2];
#pragma unroll
  for (int mt = 0; mt < 2; ++mt) {
#pragma unroll
    for (int r = 0; r < 4; ++r) lacc[mt][r] = 0.f;
#pragma unroll
    for (int nt = 0; nt < 4; ++nt)
#pragma unroll
      for (int r = 0; r < 4; ++r) oacc[mt][nt][r] = 0.f;
  }

  const int T = L / 64;
  // prologue: stage tile 0
#pragma unroll
  for (int it = 0; it < 4; ++it) {
    int c = it * 128 + tid;
    int key = c >> 3, dc = (c & 7) ^ (key & 7);
    g2lds16(&ks[base + (size_t)key * 1024 + dc * 8], &Ks[0][c * 8]);
  }
#pragma unroll
  for (int it = 0; it < 4; ++it) {
    int c = it * 128 + tid;
    int d = c >> 3, kc = (c & 7) ^ (d & 7);
    g2lds16(&vt[vtbase + (size_t)d * L + kc * 8], &Vs[0][c * 8]);
  }

  for (int t = 0; t < T; ++t) {
    __syncthreads();   // drains stage(t); prior-buf readers done
    if (t + 1 < T) {
      int k0 = (t + 1) * 64, nb = (t + 1) & 1;
#pragma unroll
      for (int it = 0; it < 4; ++it) {
        int c = it * 128 + tid;
        int key = c >> 3, dc = (c & 7) ^ (key & 7);
        g2lds16(&ks[base + (size_t)(k0 + key) * 1024 + dc * 8], &Ks[nb][c * 8]);
      }
#pragma unroll
      for (int it = 0; it < 4; ++it) {
        int c = it * 128 + tid;
        int d = c >> 3, kc = (c & 7) ^ (d & 7);
        g2lds16(&vt[vtbase + (size_t)d * L + k0 + kc * 8], &Vs[nb][c * 8]);
      }
    }
    const int cb = t & 1;

    // S = Q K^T for BOTH m-tiles with each K fragment read once
    f32x4 s[2][4];
#pragma unroll
    for (int nt = 0; nt < 4; ++nt) {
      int key = nt * 16 + l16;
      int dc0 = quad ^ (key & 7);
      int dc1 = (4 + quad) ^ (key & 7);
      bf16x8 bk0 = *reinterpret_cast<const bf16x8*>(
          &Ks[cb][(key * 8 + dc0) * 8]);
      bf16x8 bk1 = *reinterpret_cast<const bf16x8*>(
          &Ks[cb][(key * 8 + dc1) * 8]);
#pragma unroll
      for (int mt = 0; mt < 2; ++mt) {
        f32x4 z; z[0] = z[1] = z[2] = z[3] = 0.f;
        z = __builtin_amdgcn_mfma_f32_16x16x32_bf16(aq[mt][0], bk0, z, 0, 0, 0);
        z = __builtin_amdgcn_mfma_f32_16x16x32_bf16(aq[mt][1], bk1, z, 0, 0, 0);
        s[mt][nt] = z;
      }
    }

    // per m-tile: exp -> P (LDS roundtrip) -> l via ones-MFMA
    bf16x8 ap[2][2];
#pragma unroll
    for (int mt = 0; mt < 2; ++mt) {
      lds_fence();   // prior ap reads of this buffer complete
#pragma unroll
      for (int nt = 0; nt < 4; ++nt)
#pragma unroll
        for (int r = 0; r < 4; ++r)
          Ps[wave][(quad * 4 + r) * 72 + nt * 16 + l16] =
              f2b(__expf(s[mt][nt][r]));
      lds_fence();   // P writes visible to cross-lane reads
      ap[mt][0] = *reinterpret_cast<const bf16x8*>(
          &Ps[wave][l16 * 72 + quad * 8]);
      ap[mt][1] = *reinterpret_cast<const bf16x8*>(
          &Ps[wave][l16 * 72 + 32 + quad * 8]);
      lacc[mt] = __builtin_amdgcn_mfma_f32_16x16x32_bf16(ap[mt][0], ones,
                                                         lacc[mt], 0, 0, 0);
      lacc[mt] = __builtin_amdgcn_mfma_f32_16x16x32_bf16(ap[mt][1], ones,
                                                         lacc[mt], 0, 0, 0);
    }

    // O += P V (V fragments read once, used by both m-tiles)
#pragma unroll
    for (int nt = 0; nt < 4; ++nt) {
      int d = nt * 16 + l16;
#pragma unroll
      for (int hf = 0; hf < 2; ++hf) {
        int kc = (hf * 4 + quad) ^ (d & 7);
        bf16x8 bv = *reinterpret_cast<const bf16x8*>(
            &Vs[cb][(d * 8 + kc) * 8]);
#pragma unroll
        for (int mt = 0; mt < 2; ++mt)
          oacc[mt][nt] = __builtin_amdgcn_mfma_f32_16x16x32_bf16(
              ap[mt][hf], bv, oacc[mt][nt], 0, 0, 0);
      }
    }
  }

#pragma unroll
  for (int mt = 0; mt < 2; ++mt)
#pragma unroll
    for (int r = 0; r < 4; ++r) {
      float inv = 1.f / lacc[mt][r];
      int q = qb + mt * 16 + quad * 4 + r;
#pragma unroll
      for (int nt = 0; nt < 4; ++nt)
        o[base + (size_t)q * 1024 + nt * 16 + l16] =
            f2b(oacc[mt][nt][r] * inv);
    }
}

// ---------------- driver ----------------
extern "C" void kernel_launch(void* const* d_in, const int* in_sizes, int n_in,
                              void* d_out, int out_size, void* d_ws, size_t ws_size,
                              hipStream_t stream) {
  const float* X    = (const float*)d_in[0];
  const float* tq   = (const float*)d_in[1];
  const float* tk   = (const float*)d_in[2];
  const float* wkvc = (const float*)d_in[3];
  const float* wkc  = (const float*)d_in[4];
  const float* wvc  = (const float*)d_in[5];
  const float* wqr  = (const float*)d_in[6];
  const float* wkr  = (const float*)d_in[7];
  const float* wo   = (const float*)d_in[8];

  const int D = 1024, DC = 128, L = 2048;
  const int M = in_sizes[0] / D;       // B*L
  const int B = M / L;
  const int NBH = B * 16;
  (void)n_in; (void)out_size; (void)ws_size;

  unsigned short* p = (unsigned short*)d_ws;
  auto take = [&](size_t n) { unsigned short* r = p; p += n; return r; };
  unsigned short* Xb    = take((size_t)M * D);
  unsigned short* qsb   = take((size_t)M * D);
  unsigned short* ksb   = take((size_t)M * D);
  unsigned short* vcb   = take((size_t)M * D);
  unsigned short* ckv   = take((size_t)M * DC);
  unsigned short* Wbig  = take((size_t)(2 * D + DC) * D);   // [wqr|wkr|wkvc]^T
  unsigned short* Wkcvc = take((size_t)(2 * D) * DC);       // [wkc|wvc]^T
  unsigned short* WoT   = take((size_t)D * D);
  unsigned short* vtb   = Xb;   // Xb dead after fused3 gemm
  unsigned short* obuf  = vcb;  // vcb dead after vtrans; flash O lands here

  // prep
  cvt_kernel<<<(M * D / 8 + 255) / 256, 256, 0, stream>>>(X, Xb, M * D / 8);
  auto wt = [&](const float* W, unsigned short* WT, int K, int N) {
    dim3 g(N / 64, K / 64);
    wtrans_kernel<<<g, 256, 0, stream>>>(W, WT, K, N);
  };
  wt(wqr,  Wbig,                          D, D);
  wt(wkr,  Wbig + (size_t)D * D,          D, D);
  wt(wkvc, Wbig + (size_t)2 * D * D,      D, DC);
  wt(wkc,  Wkcvc,                         DC, D);
  wt(wvc,  Wkcvc + (size_t)D * DC,        DC, D);
  wt(wo,   WoT,                           D, D);

  {
    dim3 g((2 * D + DC) / 128, M / 128);                   // (17, 32)
    gemm_fused3<<<g, 256, 0, stream>>>(Xb, Wbig, qsb, ksb, ckv, D);
  }
  rope_kernel<<<(M * 512) / 256, 256, 0, stream>>>(qsb, ksb, tq, tk);
  {
    dim3 g(2 * D / 128, M / 128);                          // (16, 32)
    gemm_fused2<<<g, 256, 0, stream>>>(ckv, Wkcvc, ksb, vcb, DC);
  }

  dim3 tg(L / 64, NBH);
  vtrans_kernel<<<tg, 256, 0, stream>>>(vcb, vtb, L);

  dim3 fg(L / 64, NBH);                                    // (32, 32)
  flash8_kernel<<<fg, 128, 0, stream>>>(qsb, ksb, vtb, obuf, L);

  {
    dim3 g(D / 128, M / 64);                               // (8, 64)
    gemm_bt<64, float, false><<<g, 256, 0, stream>>>(
        obuf, WoT, (float*)d_out, M, D, D);
  }
}